// Round 14
// baseline (420.111 us; speedup 1.0000x reference)
//
#include <hip/hip_runtime.h>
#include <hip/hip_bf16.h>

// SACRSN_v84 — v14: R12 structure (best: 252us) + weight transpose in d_ws
// enabling float4 weight loads in clinear/sens/addr (4x fewer VMEM insts).
// Fallback to verified scalar path if ws_size too small.

#define NROWS 8
#define NBLOCKS 1024
#define RSTRIDE 4736

static constexpr size_t OFF_VQLOSS = 38797312UL;
static constexpr size_t OFF_IDX    = 38805504UL;
static constexpr size_t OFF_SENT   = 38813696UL;
static constexpr size_t OFF_NENT   = 38813697UL;
static constexpr size_t WS_WT_OFF  = 33280;                 // after hist(512)+rowent(32768)
static constexpr size_t WS_NEEDED  = WS_WT_OFF + (5 * 8192 + 4096) * 4;  // +176 KB

struct Params {
  const float* curr_r; const float* curr_i;
  const float* mem_r;  const float* mem_i;
  const float* codebook;
  const float* qkv_Wr; const float* qkv_Wi; const float* qkv_br; const float* qkv_bi;
  const float* quad_Wr; const float* quad_Wi; const float* quad_br; const float* quad_bi;
  const float* sens_Wr; const float* sens_Wi; const float* sens_br; const float* sens_bi;
  const float* vis_pal; const float* aud_pal;
  const float* gate_W; const float* gate_b;
  const float* addr_W; const float* addr_b;
  const float* ln_gr; const float* ln_br; const float* ln_gi; const float* ln_bi;
  float* out;
  int* hist;
  float* rowent;
  float* wt;           // ws+33280: 5 layers x (WrT 4096 | WiT 4096), then addrT 4096
};

// ---- prep: transpose weights into ws ----
__global__ __launch_bounds__(256) void prep_kernel(Params P) {
  const int bid = blockIdx.x, t = threadIdx.x;
  if (bid < 10) {
    const int layer = bid >> 1, isWi = bid & 1;
    const float* Wr_tab[5] = {P.qkv_Wr, P.qkv_Wr + 4096, P.qkv_Wr + 8192, P.quad_Wr, P.sens_Wr};
    const float* Wi_tab[5] = {P.qkv_Wi, P.qkv_Wi + 4096, P.qkv_Wi + 8192, P.quad_Wi, P.sens_Wi};
    const float* src = isWi ? Wi_tab[layer] : Wr_tab[layer];
    float* dst = P.wt + layer * 8192 + isWi * 4096;
    for (int i = t; i < 4096; i += 256) {
      const int d = i >> 6, j = i & 63;
      dst[j * 64 + d] = src[d * 64 + j];
    }
  } else {
    float* dst = P.wt + 5 * 8192;     // addrT[32][128]
    for (int i = t; i < 4096; i += 256) {
      const int d = i >> 5, l = i & 31;
      dst[l * 128 + d] = P.addr_W[d * 32 + l];
    }
  }
}

// ================= row_main: everything except VQ, one row per block =================
template <bool TW>
__global__ __launch_bounds__(256) void row_main(Params P) {
  const int b = blockIdx.x;
  const int t = threadIdx.x;
  const int lane = t & 63;
  const int wv = t >> 6;

  __shared__ __align__(16) float zr[64], zi[64];
  __shared__ float s_qr[64], s_qi[64], s_kr[64], s_ki[64], s_vr[64], s_vi[64];
  __shared__ float sfl[128];
  __shared__ float s_sp[4][4][64];
  __shared__ float lp[4][32];
  __shared__ float s_eff[32];
  __shared__ float s_sim[32], s_attn[32];
  __shared__ float s_rr[4][8][8], s_ri[4][8][8];
  __shared__ float s_pv[4][32], s_pa[4][32];
  __shared__ float s_pvp[32], s_pap[32];
  __shared__ float s_vo[128], s_ao[128];
  __shared__ float s_wg, s_gate;

  // ---- A: issue mem loads + stage z ----
  const size_t bb = (size_t)b;
  const int s = t >> 3, k = t & 7, d0 = k * 8;
  const float* mrp = P.mem_r + ((bb * 32 + s) * 64 + d0);
  const float* mip = P.mem_i + ((bb * 32 + s) * 64 + d0);
  float4 a0 = *(const float4*)mrp, a1 = *(const float4*)(mrp + 4);
  float4 b0 = *(const float4*)mip, b1 = *(const float4*)(mip + 4);
  float mr[8] = {a0.x, a0.y, a0.z, a0.w, a1.x, a1.y, a1.z, a1.w};
  float mi[8] = {b0.x, b0.y, b0.z, b0.w, b1.x, b1.y, b1.z, b1.w};

  if (t < 64)       zr[t]      = P.curr_r[bb * 64 + t];
  else if (t < 128) zi[t - 64] = P.curr_i[bb * 64 + (t - 64)];
  __syncthreads();

  float* orow = P.out + bb * RSTRIDE;

  // ---- B: clinears q,k,v,quad (wave=cl) + sens partials ----
  {
    const int j = lane, cl = wv;
    float aRR = 0.f, aRI = 0.f, aIR = 0.f, aII = 0.f;
    const float *br_, *bi_;
    if      (cl == 0) { br_ = P.qkv_br;       bi_ = P.qkv_bi;       }
    else if (cl == 1) { br_ = P.qkv_br + 64;  bi_ = P.qkv_bi + 64;  }
    else if (cl == 2) { br_ = P.qkv_br + 128; bi_ = P.qkv_bi + 128; }
    else              { br_ = P.quad_br;      bi_ = P.quad_bi;      }
    if constexpr (TW) {
      const float* WrT = P.wt + cl * 8192 + j * 64;
      const float* WiT = WrT + 4096;
      for (int d4 = 0; d4 < 64; d4 += 4) {
        const float4 wr4 = *(const float4*)&WrT[d4];
        const float4 wi4 = *(const float4*)&WiT[d4];
        const float4 xr4 = *(const float4*)&zr[d4];
        const float4 xi4 = *(const float4*)&zi[d4];
        aRR += xr4.x * wr4.x + xr4.y * wr4.y + xr4.z * wr4.z + xr4.w * wr4.w;
        aRI += xr4.x * wi4.x + xr4.y * wi4.y + xr4.z * wi4.z + xr4.w * wi4.w;
        aIR += xi4.x * wr4.x + xi4.y * wr4.y + xi4.z * wr4.z + xi4.w * wr4.w;
        aII += xi4.x * wi4.x + xi4.y * wi4.y + xi4.z * wi4.z + xi4.w * wi4.w;
      }
    } else {
      const float *Wr, *Wi;
      if      (cl == 0) { Wr = P.qkv_Wr;        Wi = P.qkv_Wi;        }
      else if (cl == 1) { Wr = P.qkv_Wr + 4096; Wi = P.qkv_Wi + 4096; }
      else if (cl == 2) { Wr = P.qkv_Wr + 8192; Wi = P.qkv_Wi + 8192; }
      else              { Wr = P.quad_Wr;       Wi = P.quad_Wi;       }
      for (int d = 0; d < 64; ++d) {
        const float xr = zr[d], xi = zi[d];
        const float wr = Wr[d * 64 + j], wi = Wi[d * 64 + j];
        aRR += xr * wr; aRI += xr * wi; aIR += xi * wr; aII += xi * wi;
      }
    }
    const float oR = (aRR + br_[j]) - (aII + bi_[j]);
    const float oI = (aRI + bi_[j]) + (aIR + br_[j]);
    if      (cl == 0) { s_qr[j] = oR; s_qi[j] = oI; }
    else if (cl == 1) { s_kr[j] = oR; s_ki[j] = oI; }
    else if (cl == 2) { s_vr[j] = oR; s_vi[j] = oI; }
    else              { orow[512 + j] = -oI; orow[576 + j] = oR; }
    // sens split-K partials (quarter = wv)
    float bRR = 0.f, bRI = 0.f, bIR = 0.f, bII = 0.f;
    if constexpr (TW) {
      const float* SrT = P.wt + 4 * 8192 + j * 64;
      const float* SiT = SrT + 4096;
      for (int d4 = wv * 16; d4 < wv * 16 + 16; d4 += 4) {
        const float4 wr4 = *(const float4*)&SrT[d4];
        const float4 wi4 = *(const float4*)&SiT[d4];
        const float4 xr4 = *(const float4*)&zr[d4];
        const float4 xi4 = *(const float4*)&zi[d4];
        bRR += xr4.x * wr4.x + xr4.y * wr4.y + xr4.z * wr4.z + xr4.w * wr4.w;
        bRI += xr4.x * wi4.x + xr4.y * wi4.y + xr4.z * wi4.z + xr4.w * wi4.w;
        bIR += xi4.x * wr4.x + xi4.y * wr4.y + xi4.z * wr4.z + xi4.w * wr4.w;
        bII += xi4.x * wi4.x + xi4.y * wi4.y + xi4.z * wi4.z + xi4.w * wi4.w;
      }
    } else {
      for (int dd = 0; dd < 16; ++dd) {
        const int d = wv * 16 + dd;
        const float xr = zr[d], xi = zi[d];
        const float wr = P.sens_Wr[d * 64 + j], wi = P.sens_Wi[d * 64 + j];
        bRR += xr * wr; bRI += xr * wi; bIR += xi * wr; bII += xi * wi;
      }
    }
    s_sp[wv][0][j] = bRR; s_sp[wv][1][j] = bRI; s_sp[wv][2][j] = bIR; s_sp[wv][3][j] = bII;
  }
  __syncthreads();

  // ---- C: sim partials (all) + addr partials (t<128) + wgate (w2) + gate (w3) ----
  {
    float sp = 0.f;
    #pragma unroll
    for (int x = 0; x < 8; ++x) sp += mr[x] * zr[d0 + x] + mi[x] * zi[d0 + x];
    sp += __shfl_xor(sp, 1); sp += __shfl_xor(sp, 2); sp += __shfl_xor(sp, 4);
    if (k == 0) s_sim[s] = sp;
  }
  if (t < 128) {
    const int q = t >> 5, l = t & 31;
    float a = 0.f;
    if constexpr (TW) {
      const float* AT = P.wt + 5 * 8192 + l * 128;
      for (int d4 = q * 32; d4 < q * 32 + 32; d4 += 4) {
        const float4 w4 = *(const float4*)&AT[d4];
        const float4 x4 = (d4 < 64) ? *(const float4*)&zr[d4] : *(const float4*)&zi[d4 - 64];
        a += x4.x * w4.x + x4.y * w4.y + x4.z * w4.z + x4.w * w4.w;
      }
    } else {
      const float* zz = (q < 2) ? zr : zi;
      const int zb = (q & 1) * 32;
      for (int i = 0; i < 32; ++i) a += zz[zb + i] * P.addr_W[(q * 32 + i) * 32 + l];
    }
    lp[q][l] = a;
  } else if (t < 192) {
    const int j = t - 128;
    float tw = zr[j] * P.gate_W[j] + zi[j] * P.gate_W[64 + j];
    #pragma unroll
    for (int m = 1; m <= 32; m <<= 1) tw += __shfl_xor(tw, m);
    if (j == 0) s_wg = tw;
  } else {
    const int j = t - 192;
    float g = s_qr[j] * s_kr[j] + s_qi[j] * s_ki[j];
    #pragma unroll
    for (int m = 1; m <= 32; m <<= 1) g += __shfl_xor(g, m);
    if (j == 0) s_gate = 1.f / (1.f + expf(-g));
  }
  __syncthreads();

  // ---- D: sim softmax (w0) | addr softmax/top3/eff (w1) | sens combine (w2) ----
  if (t < 32) {
    float v = s_sim[t];
    float mx = v;
    #pragma unroll
    for (int m = 16; m >= 1; m >>= 1) mx = fmaxf(mx, __shfl_xor(mx, m));
    float e = expf(v - mx);
    float sm = e;
    #pragma unroll
    for (int m = 16; m >= 1; m >>= 1) sm += __shfl_xor(sm, m);
    s_attn[t] = e / sm;
  } else if (t >= 64 && t < 96) {
    const int l = t - 64;
    float lg = lp[0][l] + lp[1][l] + lp[2][l] + lp[3][l] + P.addr_b[l];
    float mx = lg;
    #pragma unroll
    for (int m = 16; m >= 1; m >>= 1) mx = fmaxf(mx, __shfl_xor(mx, m));
    float e = expf(lg - mx);
    float sm = e;
    #pragma unroll
    for (int m = 16; m >= 1; m >>= 1) sm += __shfl_xor(sm, m);
    const float w = e / sm;
    float es = -(w * logf(w + 1e-10f));
    #pragma unroll
    for (int m = 16; m >= 1; m >>= 1) es += __shfl_xor(es, m);
    if (l == 0) P.rowent[b] = es;
    const float myw = w;
    bool picked = false;
    float val = w; int idx = l;
    float sumtop = 0.f;
    #pragma unroll
    for (int it = 0; it < 3; ++it) {
      float v2 = val; int i2 = idx;
      #pragma unroll
      for (int m = 16; m >= 1; m >>= 1) {
        float ov = __shfl_xor(v2, m); int oi = __shfl_xor(i2, m);
        if (ov > v2 || (ov == v2 && oi < i2)) { v2 = ov; i2 = oi; }
      }
      sumtop += v2;
      if (l == i2) { picked = true; val = -1e30f; }
    }
    const float wgate = 1.f / (1.f + expf(-(s_wg + P.gate_b[0])));
    s_eff[l] = picked ? wgate * (myw / (sumtop + 1e-6f)) : 0.f;
  } else if (t >= 128 && t < 192) {
    const int j = t - 128;
    const float aRR = s_sp[0][0][j] + s_sp[1][0][j] + s_sp[2][0][j] + s_sp[3][0][j];
    const float aRI = s_sp[0][1][j] + s_sp[1][1][j] + s_sp[2][1][j] + s_sp[3][1][j];
    const float aIR = s_sp[0][2][j] + s_sp[1][2][j] + s_sp[2][2][j] + s_sp[3][2][j];
    const float aII = s_sp[0][3][j] + s_sp[1][3][j] + s_sp[2][3][j] + s_sp[3][3][j];
    const float oR = (aRR + P.sens_br[j]) - (aII + P.sens_bi[j]);
    const float oI = (aRI + P.sens_bi[j]) + (aIR + P.sens_br[j]);
    sfl[j] = oR; sfl[64 + j] = oI;
  }
  __syncthreads();

  // ---- E: read partials + tanh/LN + palette partials ----
  const float aw = s_attn[s];
  {
    float pr[8], pi[8];
    #pragma unroll
    for (int x = 0; x < 8; ++x) { pr[x] = aw * mr[x]; pi[x] = aw * mi[x]; }
    #pragma unroll
    for (int m = 8; m <= 32; m <<= 1) {
      #pragma unroll
      for (int x = 0; x < 8; ++x) { pr[x] += __shfl_xor(pr[x], m); pi[x] += __shfl_xor(pi[x], m); }
    }
    if (lane < 8) {
      #pragma unroll
      for (int x = 0; x < 8; ++x) { s_rr[wv][lane][x] = pr[x]; s_ri[wv][lane][x] = pi[x]; }
    }
  }
  {
    const float eff = s_eff[s];
    float nr[8], ni[8];
    #pragma unroll
    for (int x = 0; x < 8; ++x) {
      nr[x] = tanhf(mr[x] + eff * (zr[d0 + x] - mr[x]));
      ni[x] = tanhf(mi[x] + eff * (zi[d0 + x] - mi[x]));
    }
    float sR = 0.f, sI = 0.f;
    #pragma unroll
    for (int x = 0; x < 8; ++x) { sR += nr[x]; sI += ni[x]; }
    sR += __shfl_xor(sR, 1); sR += __shfl_xor(sR, 2); sR += __shfl_xor(sR, 4);
    sI += __shfl_xor(sI, 1); sI += __shfl_xor(sI, 2); sI += __shfl_xor(sI, 4);
    const float mR = sR * (1.f / 64.f), mI = sI * (1.f / 64.f);
    float vR = 0.f, vI = 0.f;
    #pragma unroll
    for (int x = 0; x < 8; ++x) {
      const float dr = nr[x] - mR; vR += dr * dr;
      const float di = ni[x] - mI; vI += di * di;
    }
    vR += __shfl_xor(vR, 1); vR += __shfl_xor(vR, 2); vR += __shfl_xor(vR, 4);
    vI += __shfl_xor(vI, 1); vI += __shfl_xor(vI, 2); vI += __shfl_xor(vI, 4);
    const float invR = 1.f / sqrtf(vR * (1.f / 64.f) + 1e-6f);
    const float invI = 1.f / sqrtf(vI * (1.f / 64.f) + 1e-6f);
    float oR[8], oI[8];
    #pragma unroll
    for (int x = 0; x < 8; ++x) {
      const int d = d0 + x;
      oR[x] = (nr[x] - mR) * invR * P.ln_gr[d] + P.ln_br[d];
      oI[x] = (ni[x] - mI) * invI * P.ln_gi[d] + P.ln_bi[d];
    }
    *(float4*)&orow[640 + s * 64 + d0]      = make_float4(oR[0], oR[1], oR[2], oR[3]);
    *(float4*)&orow[640 + s * 64 + d0 + 4]  = make_float4(oR[4], oR[5], oR[6], oR[7]);
    *(float4*)&orow[2688 + s * 64 + d0]     = make_float4(oI[0], oI[1], oI[2], oI[3]);
    *(float4*)&orow[2688 + s * 64 + d0 + 4] = make_float4(oI[4], oI[5], oI[6], oI[7]);
  }
  if (t < 128) {
    const int a = t & 31, q = t >> 5;
    float sc = 0.f;
    for (int x = q * 32; x < q * 32 + 32; ++x) sc += sfl[x] * P.vis_pal[a * 128 + x];
    s_pv[q][a] = sc;
  } else {
    const int tt = t - 128, a = tt & 31, q = tt >> 5;
    float sc = 0.f;
    for (int x = q * 32; x < q * 32 + 32; ++x) sc += sfl[x] * P.aud_pal[a * 128 + x];
    s_pa[q][a] = sc;
  }
  __syncthreads();

  // ---- F: read combine (t<64) | vis softmax (w2) | aud softmax (w3) ----
  if (t < 64) {
    const int kk = t >> 3, xx = t & 7;
    const float rv = s_rr[0][kk][xx] + s_rr[1][kk][xx] + s_rr[2][kk][xx] + s_rr[3][kk][xx];
    const float iv = s_ri[0][kk][xx] + s_ri[1][kk][xx] + s_ri[2][kk][xx] + s_ri[3][kk][xx];
    orow[256 + t] = rv;
    orow[320 + t] = iv;
  } else if (t >= 128 && t < 160) {
    const int a = t - 128;
    float sc = s_pv[0][a] + s_pv[1][a] + s_pv[2][a] + s_pv[3][a];
    float mx = sc;
    #pragma unroll
    for (int m = 16; m >= 1; m >>= 1) mx = fmaxf(mx, __shfl_xor(mx, m));
    float e = expf(sc - mx);
    float sm = e;
    #pragma unroll
    for (int m = 16; m >= 1; m >>= 1) sm += __shfl_xor(sm, m);
    s_pvp[a] = e / sm;
  } else if (t >= 192 && t < 224) {
    const int a = t - 192;
    float sc = s_pa[0][a] + s_pa[1][a] + s_pa[2][a] + s_pa[3][a];
    float mx = sc;
    #pragma unroll
    for (int m = 16; m >= 1; m >>= 1) mx = fmaxf(mx, __shfl_xor(mx, m));
    float e = expf(sc - mx);
    float sm = e;
    #pragma unroll
    for (int m = 16; m >= 1; m >>= 1) sm += __shfl_xor(sm, m);
    s_pap[a] = e / sm;
  }
  __syncthreads();

  // ---- G: palette attend-out + g writes ----
  if (t < 128) {
    float v = 0.f;
    for (int a = 0; a < 32; ++a) v += s_pvp[a] * P.vis_pal[a * 128 + t];
    s_vo[t] = v;
  } else {
    const int j = t - 128;
    float v = 0.f;
    for (int a = 0; a < 32; ++a) v += s_pap[a] * P.aud_pal[a * 128 + j];
    s_ao[j] = v;
  }
  if (t < 64)       orow[128 + t] = s_vr[t] * s_gate;
  else if (t < 128) orow[192 + (t - 64)] = s_vi[t - 64] * s_gate;
  __syncthreads();

  // ---- H: exp_r / exp_i ----
  if (t < 64)       orow[384 + t] = s_vo[t] - s_ao[64 + t];
  else if (t < 128) orow[448 + (t - 64)] = s_vo[t] + s_ao[t - 64];
}

// ================= vq_kernel: unchanged (verified R11/R12) =================
__global__ __launch_bounds__(256) void vq_kernel(Params P) {
  const int t = threadIdx.x;
  const int bid = blockIdx.x;
  const int lane = t & 63;
  const int wv = t >> 6;

  __shared__ __align__(16) float s_zr[NROWS][64], s_zi[NROWS][64];
  __shared__ double s_cbn[128];
  __shared__ double s_dall[NROWS][256];
  __shared__ float s_vqls[NROWS];
  __shared__ int s_idx[NROWS];

  {
    const float* cr = P.curr_r + (size_t)bid * (NROWS * 64);
    const float* ci = P.curr_i + (size_t)bid * (NROWS * 64);
    float* zr = &s_zr[0][0];
    float* zi = &s_zi[0][0];
    for (int i = t; i < NROWS * 64; i += 256) { zr[i] = cr[i]; zi[i] = ci[i]; }
  }
  {
    const float* cb = P.codebook + (t & 127) * 128 + (t >> 7) * 64;
    double a = 0.0;
    for (int d = 0; d < 64; ++d) { double w = (double)cb[d]; a = fma(w, w, a); }
    s_dall[0][t] = a;
    __syncthreads();
    if (t < 128) s_cbn[t] = s_dall[0][t] + s_dall[0][t + 128];
    __syncthreads();
  }
  {
    const int c = t & 127, h = t >> 7;
    const float* cb = P.codebook + c * 128 + h * 64;
    const float (*zb)[64] = h ? s_zi : s_zr;
    double acc[NROWS];
    #pragma unroll
    for (int r = 0; r < NROWS; ++r) acc[r] = 0.0;
    for (int d = 0; d < 64; ++d) {
      const double w = (double)cb[d];
      #pragma unroll
      for (int r = 0; r < NROWS; ++r) acc[r] = fma(w, (double)zb[r][d], acc[r]);
    }
    #pragma unroll
    for (int r = 0; r < NROWS; ++r) s_dall[r][h * 128 + c] = acc[r];
    __syncthreads();
    #pragma unroll
    for (int rr = 0; rr < 2; ++rr) {
      const int r = wv * 2 + rr;
      const double d0 = s_cbn[lane]      - 2.0 * (s_dall[r][lane]      + s_dall[r][128 + lane]);
      const double d1 = s_cbn[lane + 64] - 2.0 * (s_dall[r][64 + lane] + s_dall[r][192 + lane]);
      double sv = d0; int si = lane;
      if (d1 < sv) { sv = d1; si = lane + 64; }
      #pragma unroll
      for (int m = 1; m <= 32; m <<= 1) {
        double ov = __shfl_xor(sv, m);
        int oi = __shfl_xor(si, m);
        if (ov < sv || (ov == sv && oi < si)) { sv = ov; si = oi; }
      }
      if (lane == 0) { s_idx[r] = si; atomicAdd(&P.hist[si], 1); }
    }
    __syncthreads();
  }
  {
    #pragma unroll
    for (int rr = 0; rr < 2; ++rr) {
      const int r = wv * 2 + rr;
      const float* cb = P.codebook + (size_t)s_idx[r] * 128;
      float d0_ = cb[lane] - s_zr[r][lane];
      float d1_ = cb[64 + lane] - s_zi[r][lane];
      float v = d0_ * d0_ + d1_ * d1_;
      #pragma unroll
      for (int m = 1; m <= 32; m <<= 1) v += __shfl_xor(v, m);
      if (lane == 0) s_vqls[r] = 0.25f * v * (1.0f / 128.0f);
    }
  }
  __syncthreads();
  {
    const int j = t & 63, g = t >> 6;
    #pragma unroll
    for (int rr = 0; rr < 4; ++rr) {
      const int r = (g >> 1) * 4 + rr;
      float* orow = P.out + ((size_t)bid * NROWS + r) * RSTRIDE;
      const float* cb = P.codebook + (size_t)s_idx[r] * 128;
      if ((g & 1) == 0) {
        float z = s_zr[r][j];
        orow[j] = z + (cb[j] - z);
      } else {
        float z = s_zi[r][j];
        orow[64 + j] = z + (cb[64 + j] - z);
      }
    }
  }
  if (t < NROWS) {
    P.out[OFF_VQLOSS + (size_t)bid * NROWS + t] = s_vqls[t];
    P.out[OFF_IDX + (size_t)bid * NROWS + t] = (float)s_idx[t];
  }
}

__global__ __launch_bounds__(256) void finalize_k(const int* hist, const float* rowent,
                                                  float* out) {
  const int t = threadIdx.x;
  __shared__ float red[256];
  float se = 0.f;
  for (int i = t; i < 8192; i += 256) se += rowent[i];
  red[t] = se;
  __syncthreads();
  for (int off = 128; off >= 1; off >>= 1) {
    if (t < off) red[t] += red[t + off];
    __syncthreads();
  }
  if (t == 0) out[OFF_SENT] = red[0] / 8192.0f;
  __syncthreads();
  float ne = 0.f;
  if (t < 128) {
    const float pp = (float)hist[t] / 8192.0f;
    ne = -(pp * logf(pp + 1e-10f));
  }
  red[t] = ne;
  __syncthreads();
  for (int off = 128; off >= 1; off >>= 1) {
    if (t < off) red[t] += red[t + off];
    __syncthreads();
  }
  if (t == 0) out[OFF_NENT] = red[0] / logf(128.0f);
}

extern "C" void kernel_launch(void* const* d_in, const int* in_sizes, int n_in,
                              void* d_out, int out_size, void* d_ws, size_t ws_size,
                              hipStream_t stream) {
  (void)in_sizes; (void)n_in; (void)out_size;
  Params P;
  P.curr_r   = (const float*)d_in[0];
  P.curr_i   = (const float*)d_in[1];
  P.mem_r    = (const float*)d_in[2];
  P.mem_i    = (const float*)d_in[3];
  P.codebook = (const float*)d_in[4];
  P.qkv_Wr   = (const float*)d_in[5];
  P.qkv_Wi   = (const float*)d_in[6];
  P.qkv_br   = (const float*)d_in[7];
  P.qkv_bi   = (const float*)d_in[8];
  P.quad_Wr  = (const float*)d_in[9];
  P.quad_Wi  = (const float*)d_in[10];
  P.quad_br  = (const float*)d_in[11];
  P.quad_bi  = (const float*)d_in[12];
  P.sens_Wr  = (const float*)d_in[13];
  P.sens_Wi  = (const float*)d_in[14];
  P.sens_br  = (const float*)d_in[15];
  P.sens_bi  = (const float*)d_in[16];
  P.vis_pal  = (const float*)d_in[17];
  P.aud_pal  = (const float*)d_in[18];
  P.gate_W   = (const float*)d_in[19];
  P.gate_b   = (const float*)d_in[20];
  P.addr_W   = (const float*)d_in[21];
  P.addr_b   = (const float*)d_in[22];
  P.ln_gr    = (const float*)d_in[23];
  P.ln_br    = (const float*)d_in[24];
  P.ln_gi    = (const float*)d_in[25];
  P.ln_bi    = (const float*)d_in[26];
  P.out = (float*)d_out;
  P.hist = (int*)d_ws;
  P.rowent = (float*)((char*)d_ws + 512);
  P.wt = (float*)((char*)d_ws + WS_WT_OFF);

  hipMemsetAsync(d_ws, 0, 512, stream);
  if (ws_size >= WS_NEEDED) {
    prep_kernel<<<dim3(11), dim3(256), 0, stream>>>(P);
    row_main<true><<<dim3(8192), dim3(256), 0, stream>>>(P);
  } else {
    row_main<false><<<dim3(8192), dim3(256), 0, stream>>>(P);
  }
  vq_kernel<<<dim3(NBLOCKS), dim3(256), 0, stream>>>(P);
  finalize_k<<<dim3(1), dim3(256), 0, stream>>>(P.hist, P.rowent, (float*)d_out);
}

// Round 15
// 269.918 us; speedup vs baseline: 1.5564x; 1.5564x over previous
//
#include <hip/hip_runtime.h>
#include <hip/hip_bf16.h>

// SACRSN_v84 — v15: R12 structure (best known) + clinear/sens weight loads
// vectorized ALONG J (float4, coalesced, 4x fewer VMEM instructions).
// R14 lesson: transposed per-lane float4 de-coalesced (64 lines/instr) — this
// scheme keeps 1KB-contiguous wave accesses. All else verbatim R12.

#define NROWS 8
#define NBLOCKS 1024
#define RSTRIDE 4736

static constexpr size_t OFF_VQLOSS = 38797312UL;
static constexpr size_t OFF_IDX    = 38805504UL;
static constexpr size_t OFF_SENT   = 38813696UL;
static constexpr size_t OFF_NENT   = 38813697UL;

struct Params {
  const float* curr_r; const float* curr_i;
  const float* mem_r;  const float* mem_i;
  const float* codebook;
  const float* qkv_Wr; const float* qkv_Wi; const float* qkv_br; const float* qkv_bi;
  const float* quad_Wr; const float* quad_Wi; const float* quad_br; const float* quad_bi;
  const float* sens_Wr; const float* sens_Wi; const float* sens_br; const float* sens_bi;
  const float* vis_pal; const float* aud_pal;
  const float* gate_W; const float* gate_b;
  const float* addr_W; const float* addr_b;
  const float* ln_gr; const float* ln_br; const float* ln_gi; const float* ln_bi;
  float* out;
  int* hist;
  float* rowent;
};

__global__ __launch_bounds__(256) void row_main(Params P) {
  const int b = blockIdx.x;
  const int t = threadIdx.x;
  const int lane = t & 63;
  const int wv = t >> 6;

  __shared__ __align__(16) float zr[64], zi[64];
  __shared__ float s_qr[64], s_qi[64], s_kr[64], s_ki[64], s_vr[64], s_vi[64];
  __shared__ float sfl[128];
  __shared__ float s_sp[4][4][64];
  __shared__ float lp[4][32];
  __shared__ float s_eff[32];
  __shared__ float s_sim[32], s_attn[32];
  __shared__ float s_rr[4][8][8], s_ri[4][8][8];
  __shared__ float s_pv[4][32], s_pa[4][32];
  __shared__ float s_pvp[32], s_pap[32];
  __shared__ float s_vo[128], s_ao[128];
  __shared__ float s_wg, s_gate;

  // ---- A: issue mem loads + stage z ----
  const size_t bb = (size_t)b;
  const int s = t >> 3, k = t & 7, d0 = k * 8;
  const float* mrp = P.mem_r + ((bb * 32 + s) * 64 + d0);
  const float* mip = P.mem_i + ((bb * 32 + s) * 64 + d0);
  float4 a0 = *(const float4*)mrp, a1 = *(const float4*)(mrp + 4);
  float4 b0 = *(const float4*)mip, b1 = *(const float4*)(mip + 4);
  float mr[8] = {a0.x, a0.y, a0.z, a0.w, a1.x, a1.y, a1.z, a1.w};
  float mi[8] = {b0.x, b0.y, b0.z, b0.w, b1.x, b1.y, b1.z, b1.w};

  if (t < 64)       zr[t]      = P.curr_r[bb * 64 + t];
  else if (t < 128) zi[t - 64] = P.curr_i[bb * 64 + (t - 64)];
  __syncthreads();

  float* orow = P.out + bb * RSTRIDE;

  // ---- B: clinears q,k,v,quad (wave=cl) + sens partials, float4-along-j ----
  {
    const int jq = lane & 15;   // j quad: j = jq*4 .. jq*4+3
    const int dh = lane >> 4;   // d sub-row 0..3
    const int cl = wv;
    const float *Wr, *Wi, *br_, *bi_;
    if      (cl == 0) { Wr = P.qkv_Wr;        Wi = P.qkv_Wi;        br_ = P.qkv_br;       bi_ = P.qkv_bi;       }
    else if (cl == 1) { Wr = P.qkv_Wr + 4096; Wi = P.qkv_Wi + 4096; br_ = P.qkv_br + 64;  bi_ = P.qkv_bi + 64;  }
    else if (cl == 2) { Wr = P.qkv_Wr + 8192; Wi = P.qkv_Wi + 8192; br_ = P.qkv_br + 128; bi_ = P.qkv_bi + 128; }
    else              { Wr = P.quad_Wr;       Wi = P.quad_Wi;       br_ = P.quad_br;      bi_ = P.quad_bi;      }
    float RR[4] = {0,0,0,0}, RI[4] = {0,0,0,0}, IR[4] = {0,0,0,0}, II[4] = {0,0,0,0};
    #pragma unroll 4
    for (int m = 0; m < 16; ++m) {
      const int d = m * 4 + dh;
      const float4 wr4 = *(const float4*)&Wr[d * 64 + jq * 4];
      const float4 wi4 = *(const float4*)&Wi[d * 64 + jq * 4];
      const float xr = zr[d], xi = zi[d];
      RR[0] += xr * wr4.x; RR[1] += xr * wr4.y; RR[2] += xr * wr4.z; RR[3] += xr * wr4.w;
      RI[0] += xr * wi4.x; RI[1] += xr * wi4.y; RI[2] += xr * wi4.z; RI[3] += xr * wi4.w;
      IR[0] += xi * wr4.x; IR[1] += xi * wr4.y; IR[2] += xi * wr4.z; IR[3] += xi * wr4.w;
      II[0] += xi * wi4.x; II[1] += xi * wi4.y; II[2] += xi * wi4.z; II[3] += xi * wi4.w;
    }
    #pragma unroll
    for (int c = 0; c < 4; ++c) {
      RR[c] += __shfl_xor(RR[c], 16); RR[c] += __shfl_xor(RR[c], 32);
      RI[c] += __shfl_xor(RI[c], 16); RI[c] += __shfl_xor(RI[c], 32);
      IR[c] += __shfl_xor(IR[c], 16); IR[c] += __shfl_xor(IR[c], 32);
      II[c] += __shfl_xor(II[c], 16); II[c] += __shfl_xor(II[c], 32);
    }
    if (dh == 0) {
      #pragma unroll
      for (int c = 0; c < 4; ++c) {
        const int j = jq * 4 + c;
        const float oR = (RR[c] + br_[j]) - (II[c] + bi_[j]);
        const float oI = (RI[c] + bi_[j]) + (IR[c] + br_[j]);
        if      (cl == 0) { s_qr[j] = oR; s_qi[j] = oI; }
        else if (cl == 1) { s_kr[j] = oR; s_ki[j] = oI; }
        else if (cl == 2) { s_vr[j] = oR; s_vi[j] = oI; }
        else              { orow[512 + j] = -oI; orow[576 + j] = oR; }
      }
    }
    // sens split-K (wave's d quarter), same scheme
    float bRR[4] = {0,0,0,0}, bRI[4] = {0,0,0,0}, bIR[4] = {0,0,0,0}, bII[4] = {0,0,0,0};
    #pragma unroll
    for (int m = 0; m < 4; ++m) {
      const int d = wv * 16 + m * 4 + dh;
      const float4 wr4 = *(const float4*)&P.sens_Wr[d * 64 + jq * 4];
      const float4 wi4 = *(const float4*)&P.sens_Wi[d * 64 + jq * 4];
      const float xr = zr[d], xi = zi[d];
      bRR[0] += xr * wr4.x; bRR[1] += xr * wr4.y; bRR[2] += xr * wr4.z; bRR[3] += xr * wr4.w;
      bRI[0] += xr * wi4.x; bRI[1] += xr * wi4.y; bRI[2] += xr * wi4.z; bRI[3] += xr * wi4.w;
      bIR[0] += xi * wr4.x; bIR[1] += xi * wr4.y; bIR[2] += xi * wr4.z; bIR[3] += xi * wr4.w;
      bII[0] += xi * wi4.x; bII[1] += xi * wi4.y; bII[2] += xi * wi4.z; bII[3] += xi * wi4.w;
    }
    #pragma unroll
    for (int c = 0; c < 4; ++c) {
      bRR[c] += __shfl_xor(bRR[c], 16); bRR[c] += __shfl_xor(bRR[c], 32);
      bRI[c] += __shfl_xor(bRI[c], 16); bRI[c] += __shfl_xor(bRI[c], 32);
      bIR[c] += __shfl_xor(bIR[c], 16); bIR[c] += __shfl_xor(bIR[c], 32);
      bII[c] += __shfl_xor(bII[c], 16); bII[c] += __shfl_xor(bII[c], 32);
    }
    if (dh == 0) {
      #pragma unroll
      for (int c = 0; c < 4; ++c) {
        const int j = jq * 4 + c;
        s_sp[wv][0][j] = bRR[c]; s_sp[wv][1][j] = bRI[c];
        s_sp[wv][2][j] = bIR[c]; s_sp[wv][3][j] = bII[c];
      }
    }
  }
  __syncthreads();

  // ---- C: sim partials (all) + addr partials (t<128) + wgate (w2) + gate (w3) ----
  {
    float sp = 0.f;
    #pragma unroll
    for (int x = 0; x < 8; ++x) sp += mr[x] * zr[d0 + x] + mi[x] * zi[d0 + x];
    sp += __shfl_xor(sp, 1); sp += __shfl_xor(sp, 2); sp += __shfl_xor(sp, 4);
    if (k == 0) s_sim[s] = sp;
  }
  if (t < 128) {
    const int q = t >> 5, l = t & 31;
    const float* zz = (q < 2) ? zr : zi;
    const int zb = (q & 1) * 32;
    float a = 0.f;
    for (int i = 0; i < 32; ++i) a += zz[zb + i] * P.addr_W[(q * 32 + i) * 32 + l];
    lp[q][l] = a;
  } else if (t < 192) {
    const int j = t - 128;
    float tw = zr[j] * P.gate_W[j] + zi[j] * P.gate_W[64 + j];
    #pragma unroll
    for (int m = 1; m <= 32; m <<= 1) tw += __shfl_xor(tw, m);
    if (j == 0) s_wg = tw;
  } else {
    const int j = t - 192;
    float g = s_qr[j] * s_kr[j] + s_qi[j] * s_ki[j];
    #pragma unroll
    for (int m = 1; m <= 32; m <<= 1) g += __shfl_xor(g, m);
    if (j == 0) s_gate = 1.f / (1.f + expf(-g));
  }
  __syncthreads();

  // ---- D: sim softmax (w0) | addr softmax/top3/eff (w1) | sens combine (w2) ----
  if (t < 32) {
    float v = s_sim[t];
    float mx = v;
    #pragma unroll
    for (int m = 16; m >= 1; m >>= 1) mx = fmaxf(mx, __shfl_xor(mx, m));
    float e = expf(v - mx);
    float sm = e;
    #pragma unroll
    for (int m = 16; m >= 1; m >>= 1) sm += __shfl_xor(sm, m);
    s_attn[t] = e / sm;
  } else if (t >= 64 && t < 96) {
    const int l = t - 64;
    float lg = lp[0][l] + lp[1][l] + lp[2][l] + lp[3][l] + P.addr_b[l];
    float mx = lg;
    #pragma unroll
    for (int m = 16; m >= 1; m >>= 1) mx = fmaxf(mx, __shfl_xor(mx, m));
    float e = expf(lg - mx);
    float sm = e;
    #pragma unroll
    for (int m = 16; m >= 1; m >>= 1) sm += __shfl_xor(sm, m);
    const float w = e / sm;
    float es = -(w * logf(w + 1e-10f));
    #pragma unroll
    for (int m = 16; m >= 1; m >>= 1) es += __shfl_xor(es, m);
    if (l == 0) P.rowent[b] = es;
    const float myw = w;
    bool picked = false;
    float val = w; int idx = l;
    float sumtop = 0.f;
    #pragma unroll
    for (int it = 0; it < 3; ++it) {
      float v2 = val; int i2 = idx;
      #pragma unroll
      for (int m = 16; m >= 1; m >>= 1) {
        float ov = __shfl_xor(v2, m); int oi = __shfl_xor(i2, m);
        if (ov > v2 || (ov == v2 && oi < i2)) { v2 = ov; i2 = oi; }
      }
      sumtop += v2;
      if (l == i2) { picked = true; val = -1e30f; }
    }
    const float wgate = 1.f / (1.f + expf(-(s_wg + P.gate_b[0])));
    s_eff[l] = picked ? wgate * (myw / (sumtop + 1e-6f)) : 0.f;
  } else if (t >= 128 && t < 192) {
    const int j = t - 128;
    const float aRR = s_sp[0][0][j] + s_sp[1][0][j] + s_sp[2][0][j] + s_sp[3][0][j];
    const float aRI = s_sp[0][1][j] + s_sp[1][1][j] + s_sp[2][1][j] + s_sp[3][1][j];
    const float aIR = s_sp[0][2][j] + s_sp[1][2][j] + s_sp[2][2][j] + s_sp[3][2][j];
    const float aII = s_sp[0][3][j] + s_sp[1][3][j] + s_sp[2][3][j] + s_sp[3][3][j];
    const float oR = (aRR + P.sens_br[j]) - (aII + P.sens_bi[j]);
    const float oI = (aRI + P.sens_bi[j]) + (aIR + P.sens_br[j]);
    sfl[j] = oR; sfl[64 + j] = oI;
  }
  __syncthreads();

  // ---- E: read partials + tanh/LN + palette partials ----
  const float aw = s_attn[s];
  {
    float pr[8], pi[8];
    #pragma unroll
    for (int x = 0; x < 8; ++x) { pr[x] = aw * mr[x]; pi[x] = aw * mi[x]; }
    #pragma unroll
    for (int m = 8; m <= 32; m <<= 1) {
      #pragma unroll
      for (int x = 0; x < 8; ++x) { pr[x] += __shfl_xor(pr[x], m); pi[x] += __shfl_xor(pi[x], m); }
    }
    if (lane < 8) {
      #pragma unroll
      for (int x = 0; x < 8; ++x) { s_rr[wv][lane][x] = pr[x]; s_ri[wv][lane][x] = pi[x]; }
    }
  }
  {
    const float eff = s_eff[s];
    float nr[8], ni[8];
    #pragma unroll
    for (int x = 0; x < 8; ++x) {
      nr[x] = tanhf(mr[x] + eff * (zr[d0 + x] - mr[x]));
      ni[x] = tanhf(mi[x] + eff * (zi[d0 + x] - mi[x]));
    }
    float sR = 0.f, sI = 0.f;
    #pragma unroll
    for (int x = 0; x < 8; ++x) { sR += nr[x]; sI += ni[x]; }
    sR += __shfl_xor(sR, 1); sR += __shfl_xor(sR, 2); sR += __shfl_xor(sR, 4);
    sI += __shfl_xor(sI, 1); sI += __shfl_xor(sI, 2); sI += __shfl_xor(sI, 4);
    const float mR = sR * (1.f / 64.f), mI = sI * (1.f / 64.f);
    float vR = 0.f, vI = 0.f;
    #pragma unroll
    for (int x = 0; x < 8; ++x) {
      const float dr = nr[x] - mR; vR += dr * dr;
      const float di = ni[x] - mI; vI += di * di;
    }
    vR += __shfl_xor(vR, 1); vR += __shfl_xor(vR, 2); vR += __shfl_xor(vR, 4);
    vI += __shfl_xor(vI, 1); vI += __shfl_xor(vI, 2); vI += __shfl_xor(vI, 4);
    const float invR = 1.f / sqrtf(vR * (1.f / 64.f) + 1e-6f);
    const float invI = 1.f / sqrtf(vI * (1.f / 64.f) + 1e-6f);
    float oR[8], oI[8];
    #pragma unroll
    for (int x = 0; x < 8; ++x) {
      const int d = d0 + x;
      oR[x] = (nr[x] - mR) * invR * P.ln_gr[d] + P.ln_br[d];
      oI[x] = (ni[x] - mI) * invI * P.ln_gi[d] + P.ln_bi[d];
    }
    *(float4*)&orow[640 + s * 64 + d0]      = make_float4(oR[0], oR[1], oR[2], oR[3]);
    *(float4*)&orow[640 + s * 64 + d0 + 4]  = make_float4(oR[4], oR[5], oR[6], oR[7]);
    *(float4*)&orow[2688 + s * 64 + d0]     = make_float4(oI[0], oI[1], oI[2], oI[3]);
    *(float4*)&orow[2688 + s * 64 + d0 + 4] = make_float4(oI[4], oI[5], oI[6], oI[7]);
  }
  if (t < 128) {
    const int a = t & 31, q = t >> 5;
    float sc = 0.f;
    for (int x = q * 32; x < q * 32 + 32; ++x) sc += sfl[x] * P.vis_pal[a * 128 + x];
    s_pv[q][a] = sc;
  } else {
    const int tt = t - 128, a = tt & 31, q = tt >> 5;
    float sc = 0.f;
    for (int x = q * 32; x < q * 32 + 32; ++x) sc += sfl[x] * P.aud_pal[a * 128 + x];
    s_pa[q][a] = sc;
  }
  __syncthreads();

  // ---- F: read combine (t<64) | vis softmax | aud softmax ----
  if (t < 64) {
    const int kk = t >> 3, xx = t & 7;
    const float rv = s_rr[0][kk][xx] + s_rr[1][kk][xx] + s_rr[2][kk][xx] + s_rr[3][kk][xx];
    const float iv = s_ri[0][kk][xx] + s_ri[1][kk][xx] + s_ri[2][kk][xx] + s_ri[3][kk][xx];
    orow[256 + t] = rv;
    orow[320 + t] = iv;
  } else if (t >= 128 && t < 160) {
    const int a = t - 128;
    float sc = s_pv[0][a] + s_pv[1][a] + s_pv[2][a] + s_pv[3][a];
    float mx = sc;
    #pragma unroll
    for (int m = 16; m >= 1; m >>= 1) mx = fmaxf(mx, __shfl_xor(mx, m));
    float e = expf(sc - mx);
    float sm = e;
    #pragma unroll
    for (int m = 16; m >= 1; m >>= 1) sm += __shfl_xor(sm, m);
    s_pvp[a] = e / sm;
  } else if (t >= 192 && t < 224) {
    const int a = t - 192;
    float sc = s_pa[0][a] + s_pa[1][a] + s_pa[2][a] + s_pa[3][a];
    float mx = sc;
    #pragma unroll
    for (int m = 16; m >= 1; m >>= 1) mx = fmaxf(mx, __shfl_xor(mx, m));
    float e = expf(sc - mx);
    float sm = e;
    #pragma unroll
    for (int m = 16; m >= 1; m >>= 1) sm += __shfl_xor(sm, m);
    s_pap[a] = e / sm;
  }
  __syncthreads();

  // ---- G: palette attend-out + g writes ----
  if (t < 128) {
    float v = 0.f;
    for (int a = 0; a < 32; ++a) v += s_pvp[a] * P.vis_pal[a * 128 + t];
    s_vo[t] = v;
  } else {
    const int j = t - 128;
    float v = 0.f;
    for (int a = 0; a < 32; ++a) v += s_pap[a] * P.aud_pal[a * 128 + j];
    s_ao[j] = v;
  }
  if (t < 64)       orow[128 + t] = s_vr[t] * s_gate;
  else if (t < 128) orow[192 + (t - 64)] = s_vi[t - 64] * s_gate;
  __syncthreads();

  // ---- H: exp_r / exp_i ----
  if (t < 64)       orow[384 + t] = s_vo[t] - s_ao[64 + t];
  else if (t < 128) orow[448 + (t - 64)] = s_vo[t] + s_ao[t - 64];
}

// ================= vq_kernel: unchanged (verified R11/R12) =================
__global__ __launch_bounds__(256) void vq_kernel(Params P) {
  const int t = threadIdx.x;
  const int bid = blockIdx.x;
  const int lane = t & 63;
  const int wv = t >> 6;

  __shared__ __align__(16) float s_zr[NROWS][64], s_zi[NROWS][64];
  __shared__ double s_cbn[128];
  __shared__ double s_dall[NROWS][256];
  __shared__ float s_vqls[NROWS];
  __shared__ int s_idx[NROWS];

  {
    const float* cr = P.curr_r + (size_t)bid * (NROWS * 64);
    const float* ci = P.curr_i + (size_t)bid * (NROWS * 64);
    float* zr = &s_zr[0][0];
    float* zi = &s_zi[0][0];
    for (int i = t; i < NROWS * 64; i += 256) { zr[i] = cr[i]; zi[i] = ci[i]; }
  }
  {
    const float* cb = P.codebook + (t & 127) * 128 + (t >> 7) * 64;
    double a = 0.0;
    for (int d = 0; d < 64; ++d) { double w = (double)cb[d]; a = fma(w, w, a); }
    s_dall[0][t] = a;
    __syncthreads();
    if (t < 128) s_cbn[t] = s_dall[0][t] + s_dall[0][t + 128];
    __syncthreads();
  }
  {
    const int c = t & 127, h = t >> 7;
    const float* cb = P.codebook + c * 128 + h * 64;
    const float (*zb)[64] = h ? s_zi : s_zr;
    double acc[NROWS];
    #pragma unroll
    for (int r = 0; r < NROWS; ++r) acc[r] = 0.0;
    for (int d = 0; d < 64; ++d) {
      const double w = (double)cb[d];
      #pragma unroll
      for (int r = 0; r < NROWS; ++r) acc[r] = fma(w, (double)zb[r][d], acc[r]);
    }
    #pragma unroll
    for (int r = 0; r < NROWS; ++r) s_dall[r][h * 128 + c] = acc[r];
    __syncthreads();
    #pragma unroll
    for (int rr = 0; rr < 2; ++rr) {
      const int r = wv * 2 + rr;
      const double d0 = s_cbn[lane]      - 2.0 * (s_dall[r][lane]      + s_dall[r][128 + lane]);
      const double d1 = s_cbn[lane + 64] - 2.0 * (s_dall[r][64 + lane] + s_dall[r][192 + lane]);
      double sv = d0; int si = lane;
      if (d1 < sv) { sv = d1; si = lane + 64; }
      #pragma unroll
      for (int m = 1; m <= 32; m <<= 1) {
        double ov = __shfl_xor(sv, m);
        int oi = __shfl_xor(si, m);
        if (ov < sv || (ov == sv && oi < si)) { sv = ov; si = oi; }
      }
      if (lane == 0) { s_idx[r] = si; atomicAdd(&P.hist[si], 1); }
    }
    __syncthreads();
  }
  {
    #pragma unroll
    for (int rr = 0; rr < 2; ++rr) {
      const int r = wv * 2 + rr;
      const float* cb = P.codebook + (size_t)s_idx[r] * 128;
      float d0_ = cb[lane] - s_zr[r][lane];
      float d1_ = cb[64 + lane] - s_zi[r][lane];
      float v = d0_ * d0_ + d1_ * d1_;
      #pragma unroll
      for (int m = 1; m <= 32; m <<= 1) v += __shfl_xor(v, m);
      if (lane == 0) s_vqls[r] = 0.25f * v * (1.0f / 128.0f);
    }
  }
  __syncthreads();
  {
    const int j = t & 63, g = t >> 6;
    #pragma unroll
    for (int rr = 0; rr < 4; ++rr) {
      const int r = (g >> 1) * 4 + rr;
      float* orow = P.out + ((size_t)bid * NROWS + r) * RSTRIDE;
      const float* cb = P.codebook + (size_t)s_idx[r] * 128;
      if ((g & 1) == 0) {
        float z = s_zr[r][j];
        orow[j] = z + (cb[j] - z);
      } else {
        float z = s_zi[r][j];
        orow[64 + j] = z + (cb[64 + j] - z);
      }
    }
  }
  if (t < NROWS) {
    P.out[OFF_VQLOSS + (size_t)bid * NROWS + t] = s_vqls[t];
    P.out[OFF_IDX + (size_t)bid * NROWS + t] = (float)s_idx[t];
  }
}

__global__ __launch_bounds__(256) void finalize_k(const int* hist, const float* rowent,
                                                  float* out) {
  const int t = threadIdx.x;
  __shared__ float red[256];
  float se = 0.f;
  for (int i = t; i < 8192; i += 256) se += rowent[i];
  red[t] = se;
  __syncthreads();
  for (int off = 128; off >= 1; off >>= 1) {
    if (t < off) red[t] += red[t + off];
    __syncthreads();
  }
  if (t == 0) out[OFF_SENT] = red[0] / 8192.0f;
  __syncthreads();
  float ne = 0.f;
  if (t < 128) {
    const float pp = (float)hist[t] / 8192.0f;
    ne = -(pp * logf(pp + 1e-10f));
  }
  red[t] = ne;
  __syncthreads();
  for (int off = 128; off >= 1; off >>= 1) {
    if (t < off) red[t] += red[t + off];
    __syncthreads();
  }
  if (t == 0) out[OFF_NENT] = red[0] / logf(128.0f);
}

extern "C" void kernel_launch(void* const* d_in, const int* in_sizes, int n_in,
                              void* d_out, int out_size, void* d_ws, size_t ws_size,
                              hipStream_t stream) {
  (void)in_sizes; (void)n_in; (void)out_size; (void)ws_size;
  Params P;
  P.curr_r   = (const float*)d_in[0];
  P.curr_i   = (const float*)d_in[1];
  P.mem_r    = (const float*)d_in[2];
  P.mem_i    = (const float*)d_in[3];
  P.codebook = (const float*)d_in[4];
  P.qkv_Wr   = (const float*)d_in[5];
  P.qkv_Wi   = (const float*)d_in[6];
  P.qkv_br   = (const float*)d_in[7];
  P.qkv_bi   = (const float*)d_in[8];
  P.quad_Wr  = (const float*)d_in[9];
  P.quad_Wi  = (const float*)d_in[10];
  P.quad_br  = (const float*)d_in[11];
  P.quad_bi  = (const float*)d_in[12];
  P.sens_Wr  = (const float*)d_in[13];
  P.sens_Wi  = (const float*)d_in[14];
  P.sens_br  = (const float*)d_in[15];
  P.sens_bi  = (const float*)d_in[16];
  P.vis_pal  = (const float*)d_in[17];
  P.aud_pal  = (const float*)d_in[18];
  P.gate_W   = (const float*)d_in[19];
  P.gate_b   = (const float*)d_in[20];
  P.addr_W   = (const float*)d_in[21];
  P.addr_b   = (const float*)d_in[22];
  P.ln_gr    = (const float*)d_in[23];
  P.ln_br    = (const float*)d_in[24];
  P.ln_gi    = (const float*)d_in[25];
  P.ln_bi    = (const float*)d_in[26];
  P.out = (float*)d_out;
  P.hist = (int*)d_ws;
  P.rowent = (float*)((char*)d_ws + 512);

  hipMemsetAsync(d_ws, 0, 512, stream);
  row_main<<<dim3(8192), dim3(256), 0, stream>>>(P);
  vq_kernel<<<dim3(NBLOCKS), dim3(256), 0, stream>>>(P);
  finalize_k<<<dim3(1), dim3(256), 0, stream>>>(P.hist, P.rowent, (float*)d_out);
}